// Round 6
// baseline (292.628 us; speedup 1.0000x reference)
//
#include <hip/hip_runtime.h>
#include <math.h>

#define MAXNORM 0.996f      // (1 - 4e-3) / sqrt(-K)
#define MINV    1e-15f
#define CLIPV   0.99999988f // f32(1 - 1e-7)

typedef _Float16 f16x8 __attribute__((ext_vector_type(8)));
typedef _Float16 h16x4 __attribute__((ext_vector_type(4)));
typedef _Float16 h16x2 __attribute__((ext_vector_type(2)));
typedef float f32x4 __attribute__((ext_vector_type(4)));

__device__ __forceinline__ float waveReduce(float v) {
#pragma unroll
    for (int off = 32; off; off >>= 1) v += __shfl_down(v, off, 64);
    return v;
}

__device__ __forceinline__ float waveAllSum(float v) {
#pragma unroll
    for (int off = 32; off; off >>= 1) v += __shfl_xor(v, off, 64);
    return v;
}

__device__ __forceinline__ float artanh_clip(float z) {
    z = fminf(z, CLIPV);
    return 0.5f * logf((1.0f + z) / (1.0f - z));
}

// split f32 -> f16 high + f16 low (Ootomo 2-term)
__device__ __forceinline__ void cvt_split8(const float4 a, const float4 b,
                                           f16x8& h, f16x8& l) {
    h[0] = (_Float16)a.x; l[0] = (_Float16)(a.x - (float)h[0]);
    h[1] = (_Float16)a.y; l[1] = (_Float16)(a.y - (float)h[1]);
    h[2] = (_Float16)a.z; l[2] = (_Float16)(a.z - (float)h[2]);
    h[3] = (_Float16)a.w; l[3] = (_Float16)(a.w - (float)h[3]);
    h[4] = (_Float16)b.x; l[4] = (_Float16)(b.x - (float)h[4]);
    h[5] = (_Float16)b.y; l[5] = (_Float16)(b.y - (float)h[5]);
    h[6] = (_Float16)b.z; l[6] = (_Float16)(b.z - (float)h[6]);
    h[7] = (_Float16)b.w; l[7] = (_Float16)(b.w - (float)h[7]);
}

// ---------------- pack W1 [256][256] + W2 [128][256] -> fragment order ----
// slot layout: Wp[(((n>>4)*8 + ks)*2 + hl)*64 + (kc&3)*16 + (n&15)]
__global__ __launch_bounds__(256) void pack_w_both(const float* __restrict__ W1,
                                                   f16x8* __restrict__ Wp1,
                                                   const float* __restrict__ W2,
                                                   f16x8* __restrict__ Wp2) {
    int idx = blockIdx.x * 256 + threadIdx.x;
    const float* W;
    f16x8* Wp;
    int n, kc;
    if (idx < 256 * 32) {
        W = W1; Wp = Wp1; n = idx >> 5; kc = idx & 31;
    } else {
        idx -= 256 * 32;
        if (idx >= 128 * 32) return;
        W = W2; Wp = Wp2; n = idx >> 5; kc = idx & 31;
    }
    const float4* p = reinterpret_cast<const float4*>(W + (size_t)n * 256 + kc * 8);
    f16x8 h, l;
    cvt_split8(p[0], p[1], h, l);
    int base = (((n >> 4) * 8 + (kc >> 2)) * 2) * 64 + (kc & 3) * 16 + (n & 15);
    Wp[base] = h;
    Wp[base + 64] = l;   // hl stride = 64 slots
}

// ---------------- kb = expmap0(b); y2 = ||kb||^2 (block 0: b1, 1: b2) ----
__global__ __launch_bounds__(256) void kb_both(const float* __restrict__ b1,
                                               float* __restrict__ kb1,
                                               const float* __restrict__ b2,
                                               float* __restrict__ kb2,
                                               float* __restrict__ y2s) {
    const int D = (blockIdx.x == 0) ? 256 : 128;
    const float* b = (blockIdx.x == 0) ? b1 : b2;
    float* kb = (blockIdx.x == 0) ? kb1 : kb2;
    float* y2o = y2s + blockIdx.x;
    __shared__ float red[4];
    int j = threadIdx.x;
    float u = (j < D) ? b[j] : 0.0f;
    float ss = waveReduce(u * u);
    if ((j & 63) == 0) red[j >> 6] = ss;
    __syncthreads();
    float tot = red[0] + red[1] + red[2] + red[3];
    float un = fmaxf(sqrtf(tot), MINV);
    float t = tanhf(un);
    float s = t / un;
    if (t > MAXNORM) s *= MAXNORM / t;
    float v = u * s;
    if (j < D) kb[j] = v;
    float ss2 = waveReduce(v * v);
    __syncthreads();
    if ((j & 63) == 0) red[j >> 6] = ss2;
    __syncthreads();
    if (j == 0) y2o[0] = red[0] + red[1] + red[2] + red[3];
}

// ---------------- MFMA split-f16 layer, register-resident epilogue --------
// acc element (mf, nf, rg) = mv[row][col]:
//   row = mf*16 + (lane>>4)*4 + rg,  col = wave*(N/4) + nf*16 + (lane&15)
template <int N, bool FUSE_EXP>
__global__ __launch_bounds__(256) void mfma_layer_kernel(
        const float* __restrict__ X,   // [n][256] raw x (FUSE_EXP) or h
        const f16x8* __restrict__ Wp,  // packed fragments
        const float* __restrict__ kb,  // [N]
        const float* __restrict__ y2p, // scalar ||kb||^2
        _Float16* __restrict__ XT,     // [n][N] f16
        int n) {
    constexpr int BM = 32, KS = 8, NF = N / 64;  // n-frags per wave
    __shared__ f16x8 sAB[2048];   // 32 slabs x 64 slots = 32 KB
    __shared__ float sXS[BM];
    __shared__ float sRedA[BM][4];
    __shared__ float sRedB[BM][4];
    __shared__ float sS[BM][4];

    const int t = threadIdx.x;
    const int wave = t >> 6, lane = t & 63;
    const size_t r0 = (size_t)blockIdx.x * BM;

    if (t < BM) sXS[t] = 0.0f;
    __syncthreads();

    // ---- stage A (f32 -> f16 h/l fragments) + row sumsq ----
    const int arow = t & 31;        // fixed row per thread
    const int kc0 = t >> 5;         // 0..7
    const bool valid = (r0 + arow) < (size_t)n;
    const float* xrow = X + (r0 + arow) * 256;
    float part = 0.0f;
#pragma unroll
    for (int i = 0; i < 4; ++i) {
        const int kc = i * 8 + kc0;
        float4 a = make_float4(0.f, 0.f, 0.f, 0.f);
        float4 b = make_float4(0.f, 0.f, 0.f, 0.f);
        if (valid) {
            a = *reinterpret_cast<const float4*>(xrow + kc * 8);
            b = *reinterpret_cast<const float4*>(xrow + kc * 8 + 4);
        }
        part += a.x * a.x + a.y * a.y + a.z * a.z + a.w * a.w +
                b.x * b.x + b.y * b.y + b.z * b.z + b.w * b.w;
        f16x8 h, l;
        cvt_split8(a, b, h, l);
        const int slab = (kc >> 2) * 4 + (arow >> 4);
        const int slot = (kc & 3) * 16 + (arow & 15);
        sAB[slab * 64 + slot] = h;
        sAB[(slab + 2) * 64 + slot] = l;
    }
    atomicAdd(&sXS[arow], part);
    __syncthreads();

    // ---- MFMA main loop ----
    f32x4 acc[2][NF];
#pragma unroll
    for (int mf = 0; mf < 2; ++mf)
#pragma unroll
        for (int nf = 0; nf < NF; ++nf) acc[mf][nf] = (f32x4){0.f, 0.f, 0.f, 0.f};

    const int nf0 = wave * NF;
#pragma unroll
    for (int ks = 0; ks < KS; ++ks) {
        const f16x8 ah0 = sAB[(ks * 4 + 0) * 64 + lane];
        const f16x8 ah1 = sAB[(ks * 4 + 1) * 64 + lane];
        const f16x8 al0 = sAB[(ks * 4 + 2) * 64 + lane];
        const f16x8 al1 = sAB[(ks * 4 + 3) * 64 + lane];
#pragma unroll
        for (int nf = 0; nf < NF; ++nf) {
            const f16x8 bh = Wp[(((nf0 + nf) * 8 + ks) * 2 + 0) * 64 + lane];
            const f16x8 bl = Wp[(((nf0 + nf) * 8 + ks) * 2 + 1) * 64 + lane];
            acc[0][nf] = __builtin_amdgcn_mfma_f32_16x16x32_f16(ah0, bh, acc[0][nf], 0, 0, 0);
            acc[1][nf] = __builtin_amdgcn_mfma_f32_16x16x32_f16(ah1, bh, acc[1][nf], 0, 0, 0);
            acc[0][nf] = __builtin_amdgcn_mfma_f32_16x16x32_f16(ah0, bl, acc[0][nf], 0, 0, 0);
            acc[1][nf] = __builtin_amdgcn_mfma_f32_16x16x32_f16(ah1, bl, acc[1][nf], 0, 0, 0);
            acc[0][nf] = __builtin_amdgcn_mfma_f32_16x16x32_f16(al0, bh, acc[0][nf], 0, 0, 0);
            acc[1][nf] = __builtin_amdgcn_mfma_f32_16x16x32_f16(al1, bh, acc[1][nf], 0, 0, 0);
        }
    }

    // ---- hoist kb columns into registers ----
    float kbv[NF];
#pragma unroll
    for (int nf = 0; nf < NF; ++nf)
        kbv[nf] = kb[wave * (N / 4) + nf * 16 + (lane & 15)];

    // ---- phase A: per-row ||mv||^2 and <mv,kb> from registers ----
#pragma unroll
    for (int mf = 0; mf < 2; ++mf)
#pragma unroll
        for (int rg = 0; rg < 4; ++rg) {
            float ms = 0.f, xy = 0.f;
#pragma unroll
            for (int nf = 0; nf < NF; ++nf) {
                const float m = acc[mf][nf][rg];
                ms = fmaf(m, m, ms);
                xy = fmaf(m, kbv[nf], xy);
            }
#pragma unroll
            for (int mask = 1; mask < 16; mask <<= 1) {
                ms += __shfl_xor(ms, mask, 64);
                xy += __shfl_xor(xy, mask, 64);
            }
            if ((lane & 15) == 0) {
                const int row = mf * 16 + (lane >> 4) * 4 + rg;
                sRedA[row][wave] = ms;
                sRedB[row][wave] = xy;
            }
        }
    __syncthreads();

    // ---- 32 parallel per-row coefficient computations ----
    const float y2 = *y2p;
    if (t < BM) {
        const int r = t;
        const float ms = sRedA[r][0] + sRedA[r][1] + sRedA[r][2] + sRedA[r][3];
        const float xy = sRedB[r][0] + sRedB[r][1] + sRedB[r][2] + sRedB[r][3];
        const float xs = sXS[r];
        const float un = fmaxf(sqrtf(xs), MINV);
        float xn0;
        if (FUSE_EXP) {
            float tt = tanhf(un);
            float alpha = tt / un;
            if (tt > MAXNORM) alpha = MAXNORM / un;
            xn0 = alpha * un;   // ||expmap0(x)||
        } else {
            xn0 = un;
        }
        const float mvn_r = fmaxf(sqrtf(ms), MINV);
        const float t1 = tanhf(mvn_r / un * artanh_clip(xn0));
        float sC = t1 / mvn_r;
        float rn = t1;
        if (t1 > MAXNORM) { sC = MAXNORM / mvn_r; rn = MAXNORM; }  // project
        const float x2 = rn * rn;
        const float xyr = sC * xy;
        const float ca = 1.0f + 2.0f * xyr + y2;
        const float cb = 1.0f - x2;
        const float den = fmaxf(1.0f + 2.0f * xyr + x2 * y2, MINV);
        sS[r][0] = ca * sC / den;  // coeff on mv
        sS[r][1] = cb / den;       // coeff on kb
    }
    __syncthreads();

    // ---- phase B: per-row ||mobius_add||^2 from registers ----
#pragma unroll
    for (int mf = 0; mf < 2; ++mf)
#pragma unroll
        for (int rg = 0; rg < 4; ++rg) {
            const int row = mf * 16 + (lane >> 4) * 4 + rg;
            const float p = sS[row][0], q = sS[row][1];
            float os = 0.f;
#pragma unroll
            for (int nf = 0; nf < NF; ++nf) {
                const float o = fmaf(p, acc[mf][nf][rg], q * kbv[nf]);
                os = fmaf(o, o, os);
            }
#pragma unroll
            for (int mask = 1; mask < 16; mask <<= 1)
                os += __shfl_xor(os, mask, 64);
            if ((lane & 15) == 0) sRedA[row][wave] = os;
        }
    __syncthreads();

    if (t < BM) {
        const float os = sRedA[t][0] + sRedA[t][1] + sRedA[t][2] + sRedA[t][3];
        float on = fmaxf(sqrtf(os), MINV);
        float s2 = (on > MAXNORM) ? (MAXNORM / on) : 1.0f;  // project
        float yn = fmaxf(on * s2, MINV);
        sS[t][2] = artanh_clip(yn) / yn * s2;               // logmap0
    }
    __syncthreads();

    // ---- write f16 output directly from registers ----
#pragma unroll
    for (int mf = 0; mf < 2; ++mf)
#pragma unroll
        for (int rg = 0; rg < 4; ++rg) {
            const int row = mf * 16 + (lane >> 4) * 4 + rg;
            if (r0 + row < (size_t)n) {
                const float p = sS[row][0], q = sS[row][1], f = sS[row][2];
                _Float16* dst = XT + (r0 + row) * N + wave * (N / 4) + (lane & 15);
#pragma unroll
                for (int nf = 0; nf < NF; ++nf)
                    dst[nf * 16] = (_Float16)(f * fmaf(p, acc[mf][nf][rg], q * kbv[nf]));
            }
        }
}

// ---------------- CSR build ----------------
__global__ void count_in_kernel(const int* __restrict__ col, int E, int* __restrict__ icnt) {
    int e = blockIdx.x * 256 + threadIdx.x;
    if (e < E) atomicAdd(&icnt[col[e]], 1);
}

// dis = rsqrt(icnt+1); offs/cursor via atomic range assignment (order-free)
__global__ void dis_kernel(const int* __restrict__ icnt, float* __restrict__ dis,
                           int* __restrict__ offs, int* __restrict__ cursor,
                           int* __restrict__ gcnt, int n) {
    int i = blockIdx.x * 256 + threadIdx.x;
    if (i < n) {
        int c = icnt[i];
        dis[i] = rsqrtf((float)(c + 1));
        int p = atomicAdd(gcnt, c);
        offs[i] = p;
        cursor[i] = p;
    }
}

// store ONLY src index; weight recomputed in gather from dis[]
__global__ void csr_scatter(const int* __restrict__ row, const int* __restrict__ col,
                            int E, int* __restrict__ cursor, int* __restrict__ csr_src) {
    int e = blockIdx.x * 256 + threadIdx.x;
    if (e >= E) return;
    int p = atomicAdd(&cursor[col[e]], 1);
    csr_src[p] = row[e];
}

// ---------------- gather (f16 rows) + expmap0: one wave per node ----------
template <int PER>
__device__ __forceinline__ void load_row(const _Float16* p, float (&v)[PER]) {
    if constexpr (PER == 4) {
        const h16x4 t = *reinterpret_cast<const h16x4*>(p);
#pragma unroll
        for (int q = 0; q < 4; ++q) v[q] = (float)t[q];
    } else {
        const h16x2 t = *reinterpret_cast<const h16x2*>(p);
#pragma unroll
        for (int q = 0; q < 2; ++q) v[q] = (float)t[q];
    }
}

template <int D>
__global__ __launch_bounds__(256) void gather_expmap_kernel(
        const _Float16* __restrict__ xt, const float* __restrict__ dis,
        const int* __restrict__ offs, const int* __restrict__ icnt,
        const int* __restrict__ csr_src,
        int n, float* __restrict__ out) {
    constexpr int PER = D / 64;  // 4 (D=256) or 2 (D=128)
    constexpr int U = 8;         // MLP depth
    int node = blockIdx.x * 4 + (threadIdx.x >> 6);
    if (node >= n) return;
    int lid = threadIdx.x & 63;
    const int loff = lid * PER;

    const float wc = dis[node];
    float acc[PER];
    {
        // self term: weight dis[c] now, x dis[c] again at the end -> dis^2
        float v[PER];
        load_row<PER>(xt + (size_t)node * D + loff, v);
#pragma unroll
        for (int q = 0; q < PER; ++q) acc[q] = wc * v[q];
    }

    const int s = offs[node];
    const int e = s + icnt[node];
    int p = s;
    for (; p + U <= e; p += U) {
        int idx[U];
#pragma unroll
        for (int u = 0; u < U; ++u) idx[u] = csr_src[p + u];
        float w[U];
#pragma unroll
        for (int u = 0; u < U; ++u) w[u] = dis[idx[u]];
        float v[U][PER];
#pragma unroll
        for (int u = 0; u < U; ++u)
            load_row<PER>(xt + (size_t)idx[u] * D + loff, v[u]);
#pragma unroll
        for (int u = 0; u < U; ++u)
#pragma unroll
            for (int q = 0; q < PER; ++q) acc[q] = fmaf(w[u], v[u][q], acc[q]);
    }
    for (; p < e; ++p) {
        const int iv = csr_src[p];
        const float w = dis[iv];
        float v[PER];
        load_row<PER>(xt + (size_t)iv * D + loff, v);
#pragma unroll
        for (int q = 0; q < PER; ++q) acc[q] = fmaf(w, v[q], acc[q]);
    }

    // final dis[c] factor, then expmap0 in-register
#pragma unroll
    for (int q = 0; q < PER; ++q) acc[q] *= wc;

    float ss = 0;
#pragma unroll
    for (int q = 0; q < PER; ++q) ss += acc[q] * acc[q];
    ss = waveAllSum(ss);
    float un = fmaxf(sqrtf(ss), MINV);
    float t = tanhf(un);
    float sc = t / un;
    if (t > MAXNORM) sc *= MAXNORM / t;

    float* op = out + (size_t)node * D + loff;
    if constexpr (PER == 4) {
        float4 o;
        o.x = sc * acc[0]; o.y = sc * acc[1]; o.z = sc * acc[2]; o.w = sc * acc[3];
        *reinterpret_cast<float4*>(op) = o;
    } else {
        float2 o;
        o.x = sc * acc[0]; o.y = sc * acc[1];
        *reinterpret_cast<float2*>(op) = o;
    }
}

extern "C" void kernel_launch(void* const* d_in, const int* in_sizes, int n_in,
                              void* d_out, int out_size, void* d_ws, size_t ws_size,
                              hipStream_t stream) {
    const float* x  = (const float*)d_in[0];
    const float* W1 = (const float*)d_in[1];
    const float* b1 = (const float*)d_in[2];
    const float* W2 = (const float*)d_in[3];
    const float* b2 = (const float*)d_in[4];
    const int*   ei = (const int*)d_in[5];

    const int N = in_sizes[0] / 256;
    const int E = in_sizes[5] / 2;
    const int* row = ei;
    const int* col = ei + E;

    float* ws = (float*)d_ws;
    size_t off = 0;
    float* A      = ws + off; off += (size_t)N * 256;            // f32 h buffer
    _Float16* C   = (_Float16*)(ws + off); off += (size_t)N * 128; // f16 xt
    f16x8* Wp1    = (f16x8*)(ws + off); off += 256 * 256;
    f16x8* Wp2    = (f16x8*)(ws + off); off += 128 * 256;
    float* kb1    = ws + off; off += 256;
    float* kb2    = ws + off; off += 128;
    float* y2s    = ws + off; off += 4;
    float* dis    = ws + off; off += N;
    int*  icnt    = (int*)(ws + off); off += N;
    int*  gcnt    = (int*)(ws + off); off += 4;
    int*  offs    = (int*)(ws + off); off += N;
    int*  cursor  = (int*)(ws + off); off += N;
    int*  csrs    = (int*)(ws + off); off += E;

    // weight prep + bias maps (fused launches)
    pack_w_both<<<(384 * 32 + 255) / 256, 256, 0, stream>>>(W1, Wp1, W2, Wp2);
    kb_both<<<2, 256, 0, stream>>>(b1, kb1, b2, kb2, y2s);

    // CSR build: in-degree -> atomic range assignment -> scatter (src only)
    hipMemsetAsync(icnt, 0, (size_t)(N + 4) * sizeof(int), stream);  // icnt + gcnt
    count_in_kernel<<<(E + 255) / 256, 256, 0, stream>>>(col, E, icnt);
    dis_kernel<<<(N + 255) / 256, 256, 0, stream>>>(icnt, dis, offs, cursor, gcnt, N);
    csr_scatter<<<(E + 255) / 256, 256, 0, stream>>>(row, col, E, cursor, csrs);

    const int nblk = (N + 31) / 32;
    // ----- layer 1 (N=256, fused expmap0 on raw x) -----
    mfma_layer_kernel<256, true><<<nblk, 256, 0, stream>>>(x, Wp1, kb1, y2s, C, N);
    gather_expmap_kernel<256><<<(N + 3) / 4, 256, 0, stream>>>(C, dis, offs, icnt, csrs, N, A);

    // ----- layer 2 (N=128) -----
    mfma_layer_kernel<128, false><<<nblk, 256, 0, stream>>>(A, Wp2, kb2, y2s + 1, C, N);
    gather_expmap_kernel<128><<<(N + 3) / 4, 256, 0, stream>>>(C, dis, offs, icnt, csrs, N, (float*)d_out);
}

// Round 7
// 280.638 us; speedup vs baseline: 1.0427x; 1.0427x over previous
//
#include <hip/hip_runtime.h>
#include <math.h>

#define MAXNORM 0.996f      // (1 - 4e-3) / sqrt(-K)
#define MINV    1e-15f
#define CLIPV   0.99999988f // f32(1 - 1e-7)

typedef _Float16 f16x8 __attribute__((ext_vector_type(8)));
typedef _Float16 h16x4 __attribute__((ext_vector_type(4)));
typedef _Float16 h16x2 __attribute__((ext_vector_type(2)));
typedef float f32x4 __attribute__((ext_vector_type(4)));

__device__ __forceinline__ float waveReduce(float v) {
#pragma unroll
    for (int off = 32; off; off >>= 1) v += __shfl_down(v, off, 64);
    return v;
}

__device__ __forceinline__ float waveAllSum(float v) {
#pragma unroll
    for (int off = 32; off; off >>= 1) v += __shfl_xor(v, off, 64);
    return v;
}

__device__ __forceinline__ float artanh_clip(float z) {
    z = fminf(z, CLIPV);
    return 0.5f * logf((1.0f + z) / (1.0f - z));
}

// split f32 -> f16 high + f16 low (Ootomo 2-term)
__device__ __forceinline__ void cvt_split8(const float4 a, const float4 b,
                                           f16x8& h, f16x8& l) {
    h[0] = (_Float16)a.x; l[0] = (_Float16)(a.x - (float)h[0]);
    h[1] = (_Float16)a.y; l[1] = (_Float16)(a.y - (float)h[1]);
    h[2] = (_Float16)a.z; l[2] = (_Float16)(a.z - (float)h[2]);
    h[3] = (_Float16)a.w; l[3] = (_Float16)(a.w - (float)h[3]);
    h[4] = (_Float16)b.x; l[4] = (_Float16)(b.x - (float)h[4]);
    h[5] = (_Float16)b.y; l[5] = (_Float16)(b.y - (float)h[5]);
    h[6] = (_Float16)b.z; l[6] = (_Float16)(b.z - (float)h[6]);
    h[7] = (_Float16)b.w; l[7] = (_Float16)(b.w - (float)h[7]);
}

// ---------------- pack W1 [256][256] + W2 [128][256] -> fragment order ----
// slot layout: Wp[(((n>>4)*8 + ks)*2 + hl)*64 + (kc&3)*16 + (n&15)]
__global__ __launch_bounds__(256) void pack_w_both(const float* __restrict__ W1,
                                                   f16x8* __restrict__ Wp1,
                                                   const float* __restrict__ W2,
                                                   f16x8* __restrict__ Wp2) {
    int idx = blockIdx.x * 256 + threadIdx.x;
    const float* W;
    f16x8* Wp;
    int n, kc;
    if (idx < 256 * 32) {
        W = W1; Wp = Wp1; n = idx >> 5; kc = idx & 31;
    } else {
        idx -= 256 * 32;
        if (idx >= 128 * 32) return;
        W = W2; Wp = Wp2; n = idx >> 5; kc = idx & 31;
    }
    const float4* p = reinterpret_cast<const float4*>(W + (size_t)n * 256 + kc * 8);
    f16x8 h, l;
    cvt_split8(p[0], p[1], h, l);
    int base = (((n >> 4) * 8 + (kc >> 2)) * 2) * 64 + (kc & 3) * 16 + (n & 15);
    Wp[base] = h;
    Wp[base + 64] = l;   // hl stride = 64 slots
}

// ---------------- kb = expmap0(b); y2 = ||kb||^2 (block 0: b1, 1: b2) ----
__global__ __launch_bounds__(256) void kb_both(const float* __restrict__ b1,
                                               float* __restrict__ kb1,
                                               const float* __restrict__ b2,
                                               float* __restrict__ kb2,
                                               float* __restrict__ y2s) {
    const int D = (blockIdx.x == 0) ? 256 : 128;
    const float* b = (blockIdx.x == 0) ? b1 : b2;
    float* kb = (blockIdx.x == 0) ? kb1 : kb2;
    float* y2o = y2s + blockIdx.x;
    __shared__ float red[4];
    int j = threadIdx.x;
    float u = (j < D) ? b[j] : 0.0f;
    float ss = waveReduce(u * u);
    if ((j & 63) == 0) red[j >> 6] = ss;
    __syncthreads();
    float tot = red[0] + red[1] + red[2] + red[3];
    float un = fmaxf(sqrtf(tot), MINV);
    float t = tanhf(un);
    float s = t / un;
    if (t > MAXNORM) s *= MAXNORM / t;
    float v = u * s;
    if (j < D) kb[j] = v;
    float ss2 = waveReduce(v * v);
    __syncthreads();
    if ((j & 63) == 0) red[j >> 6] = ss2;
    __syncthreads();
    if (j == 0) y2o[0] = red[0] + red[1] + red[2] + red[3];
}

// ---------------- MFMA split-f16 layer, register-resident epilogue --------
// Output is PREMULTIPLIED by dis[row]: XT[r] = dis[r] * logmap0(...)
// acc element (mf, nf, rg) = mv[row][col]:
//   row = mf*16 + (lane>>4)*4 + rg,  col = wave*(N/4) + nf*16 + (lane&15)
template <int N, bool FUSE_EXP>
__global__ __launch_bounds__(256) void mfma_layer_kernel(
        const float* __restrict__ X,   // [n][256] raw x (FUSE_EXP) or h
        const f16x8* __restrict__ Wp,  // packed fragments
        const float* __restrict__ kb,  // [N]
        const float* __restrict__ y2p, // scalar ||kb||^2
        const float* __restrict__ dis, // [n] rsqrt(deg)
        _Float16* __restrict__ XT,     // [n][N] f16, dis-premultiplied
        int n) {
    constexpr int BM = 32, KS = 8, NF = N / 64;  // n-frags per wave
    __shared__ f16x8 sAB[2048];   // 32 slabs x 64 slots = 32 KB
    __shared__ float sXS[BM];
    __shared__ float sRedA[BM][4];
    __shared__ float sRedB[BM][4];
    __shared__ float sS[BM][4];

    const int t = threadIdx.x;
    const int wave = t >> 6, lane = t & 63;
    const size_t r0 = (size_t)blockIdx.x * BM;

    if (t < BM) sXS[t] = 0.0f;
    __syncthreads();

    // ---- stage A (f32 -> f16 h/l fragments) + row sumsq ----
    const int arow = t & 31;        // fixed row per thread
    const int kc0 = t >> 5;         // 0..7
    const bool valid = (r0 + arow) < (size_t)n;
    const float* xrow = X + (r0 + arow) * 256;
    float part = 0.0f;
#pragma unroll
    for (int i = 0; i < 4; ++i) {
        const int kc = i * 8 + kc0;
        float4 a = make_float4(0.f, 0.f, 0.f, 0.f);
        float4 b = make_float4(0.f, 0.f, 0.f, 0.f);
        if (valid) {
            a = *reinterpret_cast<const float4*>(xrow + kc * 8);
            b = *reinterpret_cast<const float4*>(xrow + kc * 8 + 4);
        }
        part += a.x * a.x + a.y * a.y + a.z * a.z + a.w * a.w +
                b.x * b.x + b.y * b.y + b.z * b.z + b.w * b.w;
        f16x8 h, l;
        cvt_split8(a, b, h, l);
        const int slab = (kc >> 2) * 4 + (arow >> 4);
        const int slot = (kc & 3) * 16 + (arow & 15);
        sAB[slab * 64 + slot] = h;
        sAB[(slab + 2) * 64 + slot] = l;
    }
    atomicAdd(&sXS[arow], part);
    __syncthreads();

    // ---- MFMA main loop ----
    f32x4 acc[2][NF];
#pragma unroll
    for (int mf = 0; mf < 2; ++mf)
#pragma unroll
        for (int nf = 0; nf < NF; ++nf) acc[mf][nf] = (f32x4){0.f, 0.f, 0.f, 0.f};

    const int nf0 = wave * NF;
#pragma unroll
    for (int ks = 0; ks < KS; ++ks) {
        const f16x8 ah0 = sAB[(ks * 4 + 0) * 64 + lane];
        const f16x8 ah1 = sAB[(ks * 4 + 1) * 64 + lane];
        const f16x8 al0 = sAB[(ks * 4 + 2) * 64 + lane];
        const f16x8 al1 = sAB[(ks * 4 + 3) * 64 + lane];
#pragma unroll
        for (int nf = 0; nf < NF; ++nf) {
            const f16x8 bh = Wp[(((nf0 + nf) * 8 + ks) * 2 + 0) * 64 + lane];
            const f16x8 bl = Wp[(((nf0 + nf) * 8 + ks) * 2 + 1) * 64 + lane];
            acc[0][nf] = __builtin_amdgcn_mfma_f32_16x16x32_f16(ah0, bh, acc[0][nf], 0, 0, 0);
            acc[1][nf] = __builtin_amdgcn_mfma_f32_16x16x32_f16(ah1, bh, acc[1][nf], 0, 0, 0);
            acc[0][nf] = __builtin_amdgcn_mfma_f32_16x16x32_f16(ah0, bl, acc[0][nf], 0, 0, 0);
            acc[1][nf] = __builtin_amdgcn_mfma_f32_16x16x32_f16(ah1, bl, acc[1][nf], 0, 0, 0);
            acc[0][nf] = __builtin_amdgcn_mfma_f32_16x16x32_f16(al0, bh, acc[0][nf], 0, 0, 0);
            acc[1][nf] = __builtin_amdgcn_mfma_f32_16x16x32_f16(al1, bh, acc[1][nf], 0, 0, 0);
        }
    }

    // ---- hoist kb columns into registers ----
    float kbv[NF];
#pragma unroll
    for (int nf = 0; nf < NF; ++nf)
        kbv[nf] = kb[wave * (N / 4) + nf * 16 + (lane & 15)];

    // ---- phase A: per-row ||mv||^2 and <mv,kb> from registers ----
#pragma unroll
    for (int mf = 0; mf < 2; ++mf)
#pragma unroll
        for (int rg = 0; rg < 4; ++rg) {
            float ms = 0.f, xy = 0.f;
#pragma unroll
            for (int nf = 0; nf < NF; ++nf) {
                const float m = acc[mf][nf][rg];
                ms = fmaf(m, m, ms);
                xy = fmaf(m, kbv[nf], xy);
            }
#pragma unroll
            for (int mask = 1; mask < 16; mask <<= 1) {
                ms += __shfl_xor(ms, mask, 64);
                xy += __shfl_xor(xy, mask, 64);
            }
            if ((lane & 15) == 0) {
                const int row = mf * 16 + (lane >> 4) * 4 + rg;
                sRedA[row][wave] = ms;
                sRedB[row][wave] = xy;
            }
        }
    __syncthreads();

    // ---- 32 parallel per-row coefficient computations ----
    const float y2 = *y2p;
    if (t < BM) {
        const int r = t;
        const float ms = sRedA[r][0] + sRedA[r][1] + sRedA[r][2] + sRedA[r][3];
        const float xy = sRedB[r][0] + sRedB[r][1] + sRedB[r][2] + sRedB[r][3];
        const float xs = sXS[r];
        const float un = fmaxf(sqrtf(xs), MINV);
        float xn0;
        if (FUSE_EXP) {
            float tt = tanhf(un);
            float alpha = tt / un;
            if (tt > MAXNORM) alpha = MAXNORM / un;
            xn0 = alpha * un;   // ||expmap0(x)||
        } else {
            xn0 = un;
        }
        const float mvn_r = fmaxf(sqrtf(ms), MINV);
        const float t1 = tanhf(mvn_r / un * artanh_clip(xn0));
        float sC = t1 / mvn_r;
        float rn = t1;
        if (t1 > MAXNORM) { sC = MAXNORM / mvn_r; rn = MAXNORM; }  // project
        const float x2 = rn * rn;
        const float xyr = sC * xy;
        const float ca = 1.0f + 2.0f * xyr + y2;
        const float cb = 1.0f - x2;
        const float den = fmaxf(1.0f + 2.0f * xyr + x2 * y2, MINV);
        sS[r][0] = ca * sC / den;  // coeff on mv
        sS[r][1] = cb / den;       // coeff on kb
    }
    __syncthreads();

    // ---- phase B: per-row ||mobius_add||^2 from registers ----
#pragma unroll
    for (int mf = 0; mf < 2; ++mf)
#pragma unroll
        for (int rg = 0; rg < 4; ++rg) {
            const int row = mf * 16 + (lane >> 4) * 4 + rg;
            const float p = sS[row][0], q = sS[row][1];
            float os = 0.f;
#pragma unroll
            for (int nf = 0; nf < NF; ++nf) {
                const float o = fmaf(p, acc[mf][nf][rg], q * kbv[nf]);
                os = fmaf(o, o, os);
            }
#pragma unroll
            for (int mask = 1; mask < 16; mask <<= 1)
                os += __shfl_xor(os, mask, 64);
            if ((lane & 15) == 0) sRedA[row][wave] = os;
        }
    __syncthreads();

    if (t < BM) {
        const float os = sRedA[t][0] + sRedA[t][1] + sRedA[t][2] + sRedA[t][3];
        float on = fmaxf(sqrtf(os), MINV);
        float s2 = (on > MAXNORM) ? (MAXNORM / on) : 1.0f;  // project
        float yn = fmaxf(on * s2, MINV);
        const float dv = (r0 + t < (size_t)n) ? dis[r0 + t] : 0.0f;
        sS[t][2] = artanh_clip(yn) / yn * s2 * dv;          // logmap0 * dis
    }
    __syncthreads();

    // ---- write f16 output directly from registers ----
#pragma unroll
    for (int mf = 0; mf < 2; ++mf)
#pragma unroll
        for (int rg = 0; rg < 4; ++rg) {
            const int row = mf * 16 + (lane >> 4) * 4 + rg;
            if (r0 + row < (size_t)n) {
                const float p = sS[row][0], q = sS[row][1], f = sS[row][2];
                _Float16* dst = XT + (r0 + row) * N + wave * (N / 4) + (lane & 15);
#pragma unroll
                for (int nf = 0; nf < NF; ++nf)
                    dst[nf * 16] = (_Float16)(f * fmaf(p, acc[mf][nf][rg], q * kbv[nf]));
            }
        }
}

// ---------------- CSR build ----------------
__global__ void count_in_kernel(const int* __restrict__ col, int E, int* __restrict__ icnt) {
    int e = blockIdx.x * 256 + threadIdx.x;
    if (e < E) atomicAdd(&icnt[col[e]], 1);
}

// dis = rsqrt(icnt+1); offs/cursor via atomic range assignment (order-free)
__global__ void dis_kernel(const int* __restrict__ icnt, float* __restrict__ dis,
                           int* __restrict__ offs, int* __restrict__ cursor,
                           int* __restrict__ gcnt, int n) {
    int i = blockIdx.x * 256 + threadIdx.x;
    if (i < n) {
        int c = icnt[i];
        dis[i] = rsqrtf((float)(c + 1));
        int p = atomicAdd(gcnt, c);
        offs[i] = p;
        cursor[i] = p;
    }
}

// store ONLY src index; weights are baked into xt
__global__ void csr_scatter(const int* __restrict__ row, const int* __restrict__ col,
                            int E, int* __restrict__ cursor, int* __restrict__ csr_src) {
    int e = blockIdx.x * 256 + threadIdx.x;
    if (e >= E) return;
    int p = atomicAdd(&cursor[col[e]], 1);
    csr_src[p] = row[e];
}

// ---------------- gather (dis-premultiplied f16 rows) + expmap0 -----------
// out[c] = expmap0( dis[c] * ( sum_{edges} xt[src] + xt[c] ) )
template <int PER>
__device__ __forceinline__ void load_row(const _Float16* p, float (&v)[PER]) {
    if constexpr (PER == 4) {
        const h16x4 t = *reinterpret_cast<const h16x4*>(p);
#pragma unroll
        for (int q = 0; q < 4; ++q) v[q] = (float)t[q];
    } else {
        const h16x2 t = *reinterpret_cast<const h16x2*>(p);
#pragma unroll
        for (int q = 0; q < 2; ++q) v[q] = (float)t[q];
    }
}

template <int D>
__global__ __launch_bounds__(256) void gather_expmap_kernel(
        const _Float16* __restrict__ xt, const float* __restrict__ dis,
        const int* __restrict__ offs, const int* __restrict__ icnt,
        const int* __restrict__ csr_src,
        int n, float* __restrict__ out) {
    constexpr int PER = D / 64;  // 4 (D=256) or 2 (D=128)
    constexpr int U = 8;         // MLP depth
    int node = blockIdx.x * 4 + (threadIdx.x >> 6);
    if (node >= n) return;
    int lid = threadIdx.x & 63;
    const int loff = lid * PER;

    float acc[PER];
    {
        float v[PER];
        load_row<PER>(xt + (size_t)node * D + loff, v);  // self row
#pragma unroll
        for (int q = 0; q < PER; ++q) acc[q] = v[q];
    }

    const int s = offs[node];
    const int e = s + icnt[node];
    int p = s;
    // full batches: pure idx -> row -> add (chain depth 2)
    for (; p + U <= e; p += U) {
        int idx[U];
#pragma unroll
        for (int u = 0; u < U; ++u) idx[u] = csr_src[p + u];
        float v[U][PER];
#pragma unroll
        for (int u = 0; u < U; ++u)
            load_row<PER>(xt + (size_t)idx[u] * D + loff, v[u]);
#pragma unroll
        for (int u = 0; u < U; ++u)
#pragma unroll
            for (int q = 0; q < PER; ++q) acc[q] += v[u][q];
    }
    // masked tail batch: all loads issue in parallel, 0/1 weight
    if (p < e) {
        int idx[U];
        float m[U];
#pragma unroll
        for (int u = 0; u < U; ++u) {
            const bool ok = (p + u) < e;
            idx[u] = csr_src[ok ? (p + u) : (e - 1)];
            m[u] = ok ? 1.0f : 0.0f;
        }
        float v[U][PER];
#pragma unroll
        for (int u = 0; u < U; ++u)
            load_row<PER>(xt + (size_t)idx[u] * D + loff, v[u]);
#pragma unroll
        for (int u = 0; u < U; ++u)
#pragma unroll
            for (int q = 0; q < PER; ++q) acc[q] = fmaf(m[u], v[u][q], acc[q]);
    }

    // final dis[c] factor, then expmap0 in-register
    const float wc = dis[node];
#pragma unroll
    for (int q = 0; q < PER; ++q) acc[q] *= wc;

    float ss = 0;
#pragma unroll
    for (int q = 0; q < PER; ++q) ss += acc[q] * acc[q];
    ss = waveAllSum(ss);
    float un = fmaxf(sqrtf(ss), MINV);
    float t = tanhf(un);
    float sc = t / un;
    if (t > MAXNORM) sc *= MAXNORM / t;

    float* op = out + (size_t)node * D + loff;
    if constexpr (PER == 4) {
        float4 o;
        o.x = sc * acc[0]; o.y = sc * acc[1]; o.z = sc * acc[2]; o.w = sc * acc[3];
        *reinterpret_cast<float4*>(op) = o;
    } else {
        float2 o;
        o.x = sc * acc[0]; o.y = sc * acc[1];
        *reinterpret_cast<float2*>(op) = o;
    }
}

extern "C" void kernel_launch(void* const* d_in, const int* in_sizes, int n_in,
                              void* d_out, int out_size, void* d_ws, size_t ws_size,
                              hipStream_t stream) {
    const float* x  = (const float*)d_in[0];
    const float* W1 = (const float*)d_in[1];
    const float* b1 = (const float*)d_in[2];
    const float* W2 = (const float*)d_in[3];
    const float* b2 = (const float*)d_in[4];
    const int*   ei = (const int*)d_in[5];

    const int N = in_sizes[0] / 256;
    const int E = in_sizes[5] / 2;
    const int* row = ei;
    const int* col = ei + E;

    float* ws = (float*)d_ws;
    size_t off = 0;
    float* A      = ws + off; off += (size_t)N * 256;            // f32 h buffer
    _Float16* C   = (_Float16*)(ws + off); off += (size_t)N * 128; // f16 xt
    f16x8* Wp1    = (f16x8*)(ws + off); off += 256 * 256;
    f16x8* Wp2    = (f16x8*)(ws + off); off += 128 * 256;
    float* kb1    = ws + off; off += 256;
    float* kb2    = ws + off; off += 128;
    float* y2s    = ws + off; off += 4;
    float* dis    = ws + off; off += N;
    int*  icnt    = (int*)(ws + off); off += N;
    int*  gcnt    = (int*)(ws + off); off += 4;
    int*  offs    = (int*)(ws + off); off += N;
    int*  cursor  = (int*)(ws + off); off += N;
    int*  csrs    = (int*)(ws + off); off += E;

    // weight prep + bias maps (fused launches)
    pack_w_both<<<(384 * 32 + 255) / 256, 256, 0, stream>>>(W1, Wp1, W2, Wp2);
    kb_both<<<2, 256, 0, stream>>>(b1, kb1, b2, kb2, y2s);

    // CSR build: in-degree -> atomic range assignment -> scatter (src only)
    hipMemsetAsync(icnt, 0, (size_t)(N + 4) * sizeof(int), stream);  // icnt + gcnt
    count_in_kernel<<<(E + 255) / 256, 256, 0, stream>>>(col, E, icnt);
    dis_kernel<<<(N + 255) / 256, 256, 0, stream>>>(icnt, dis, offs, cursor, gcnt, N);
    csr_scatter<<<(E + 255) / 256, 256, 0, stream>>>(row, col, E, cursor, csrs);

    const int nblk = (N + 31) / 32;
    // ----- layer 1 (N=256, fused expmap0 on raw x) -----
    mfma_layer_kernel<256, true><<<nblk, 256, 0, stream>>>(x, Wp1, kb1, y2s, dis, C, N);
    gather_expmap_kernel<256><<<(N + 3) / 4, 256, 0, stream>>>(C, dis, offs, icnt, csrs, N, A);

    // ----- layer 2 (N=128) -----
    mfma_layer_kernel<128, false><<<nblk, 256, 0, stream>>>(A, Wp2, kb2, y2s + 1, dis, C, N);
    gather_expmap_kernel<128><<<(N + 3) / 4, 256, 0, stream>>>(C, dis, offs, icnt, csrs, N, (float*)d_out);
}